// Round 2
// baseline (1584.168 us; speedup 1.0000x reference)
//
#include <hip/hip_runtime.h>

#define LOG20F 2.9957322735539909f

typedef __attribute__((ext_vector_type(4))) short short4v;
typedef __attribute__((ext_vector_type(8))) short short8;
typedef __attribute__((ext_vector_type(8))) __bf16 bf16x8;
typedef __attribute__((ext_vector_type(4))) float f32x4;

__device__ __forceinline__ short f2bf(float f) {
  unsigned u = __float_as_uint(f);
  u = u + 0x7fffu + ((u >> 16) & 1u);   // RNE
  return (short)(u >> 16);
}
__device__ __forceinline__ float bf2f(short s) {
  return __uint_as_float(((unsigned)(unsigned short)s) << 16);
}

// LDS tile layout: [rows][32 bf16] with XOR swizzle on the 16B chunk index.
// chunk ^= (row>>1)&3 makes any 16 consecutive rows hit each 16B slot exactly
// 2x -> 2-way aliasing = free (m136).
__device__ __forceinline__ int swz(int row, int ch) {
  return row * 32 + ((ch ^ ((row >> 1) & 3)) << 3);   // offset in shorts
}

// ---------------------------------------------------------------------------
// BT GEMM: C[i,j] = sum_k A[i,k]*B[j,k], A:(M,K) ld=lda, B:(N,K) ld=ldb, both
// bf16 row-major along K. C bf16 (M,N) ld=ldc. EPI: 0=scale, 1=+add(bf16),
// 2=bn+silu (per-col scale/shift).
// ---------------------------------------------------------------------------
template <int BM, int BN, int WR, int WC, int EPI>
__global__ __launch_bounds__(256, 2) void gemm_bt(
    const short* __restrict__ A, const short* __restrict__ B,
    short* __restrict__ C, const short* __restrict__ addp,
    const float* __restrict__ sc, const float* __restrict__ sh,
    int K, int lda, int ldb, int ldc,
    long abatch, long bbatch, long cbatch, float scale)
{
  constexpr int WM = BM / WR, WN = BN / WC;
  constexpr int MR = WM / 16, NR = WN / 16;
  constexpr int CA = BM / 64, CB = BN / 64;   // 16B chunks per thread

  __shared__ short lA[2][BM * 32];
  __shared__ short lB[2][BN * 32];

  const int tid = threadIdx.x;
  const int lane = tid & 63, wid = tid >> 6;
  const int wr = wid / WC, wc = wid % WC;

  const long bm = (long)blockIdx.x * BM, bn = (long)blockIdx.y * BN;
  const short* Ab = A + (long)blockIdx.z * abatch + bm * lda;
  const short* Bb = B + (long)blockIdx.z * bbatch + bn * ldb;

  f32x4 acc[MR][NR] = {};
  short8 ra[CA], rb[CB];

  auto loadg = [&](int k0) {
#pragma unroll
    for (int i = 0; i < CA; ++i) {
      int idx = i * 256 + tid, row = idx >> 2, ch = idx & 3;
      ra[i] = *(const short8*)(Ab + (long)row * lda + k0 + ch * 8);
    }
#pragma unroll
    for (int i = 0; i < CB; ++i) {
      int idx = i * 256 + tid, row = idx >> 2, ch = idx & 3;
      rb[i] = *(const short8*)(Bb + (long)row * ldb + k0 + ch * 8);
    }
  };
  auto stage = [&](int buf) {
#pragma unroll
    for (int i = 0; i < CA; ++i) {
      int idx = i * 256 + tid, row = idx >> 2, ch = idx & 3;
      *(short8*)&lA[buf][swz(row, ch)] = ra[i];
    }
#pragma unroll
    for (int i = 0; i < CB; ++i) {
      int idx = i * 256 + tid, row = idx >> 2, ch = idx & 3;
      *(short8*)&lB[buf][swz(row, ch)] = rb[i];
    }
  };

  const int NT = K >> 5;   // BK=32
  loadg(0);
  stage(0);
  int cur = 0;
  for (int t = 0; t < NT; ++t) {
    if (t + 1 < NT) loadg((t + 1) << 5);   // issue next-tile loads early
    __syncthreads();                       // staged buf[cur] visible
    const int ch = lane >> 4, rrow = lane & 15;
    bf16x8 af[MR], bfr[NR];
#pragma unroll
    for (int mi = 0; mi < MR; ++mi) {
      int row = wr * WM + mi * 16 + rrow;
      af[mi] = *(const bf16x8*)&lA[cur][swz(row, ch)];
    }
#pragma unroll
    for (int ni = 0; ni < NR; ++ni) {
      int row = wc * WN + ni * 16 + rrow;
      bfr[ni] = *(const bf16x8*)&lB[cur][swz(row, ch)];
    }
#pragma unroll
    for (int mi = 0; mi < MR; ++mi)
#pragma unroll
      for (int ni = 0; ni < NR; ++ni)
        acc[mi][ni] = __builtin_amdgcn_mfma_f32_16x16x32_bf16(
            af[mi], bfr[ni], acc[mi][ni], 0, 0, 0);
    if (t + 1 < NT) stage(cur ^ 1);        // dbuf write, no extra barrier needed
    cur ^= 1;
  }

  // epilogue: D lane map col=lane&15, row=(lane>>4)*4+r (m89/m91)
#pragma unroll
  for (int mi = 0; mi < MR; ++mi) {
    long row0 = bm + wr * WM + mi * 16 + ((lane >> 4) << 2);
#pragma unroll
    for (int ni = 0; ni < NR; ++ni) {
      long col = bn + wc * WN + ni * 16 + (lane & 15);
#pragma unroll
      for (int r = 0; r < 4; ++r) {
        long off = (long)blockIdx.z * cbatch + (row0 + r) * ldc + col;
        float v = acc[mi][ni][r] * scale;
        if constexpr (EPI == 1) v += bf2f(addp[off]);
        if constexpr (EPI == 2) {
          float y = v * sc[col] + sh[col];
          v = y / (1.f + __expf(-y));
        }
        C[off] = f2bf(v);
      }
    }
  }
}

// ---------------------------------------------------------------------------
// (z,C,N) f32 -> (z,N,C) bf16 tiled transpose-convert
// ---------------------------------------------------------------------------
__global__ __launch_bounds__(256) void transpose_cvt(
    const float* __restrict__ in, short* __restrict__ out, int C, int N)
{
  __shared__ float tile[32][33];
  int n0 = blockIdx.x * 32, c0 = blockIdx.y * 32;
  long z = (long)blockIdx.z * C * N;
  int tx = threadIdx.x & 31, ty = threadIdx.x >> 5;   // ty 0..7
#pragma unroll
  for (int r = 0; r < 4; ++r) {
    int cc = ty + r * 8;
    tile[cc][tx] = in[z + (long)(c0 + cc) * N + n0 + tx];
  }
  __syncthreads();
#pragma unroll
  for (int r = 0; r < 4; ++r) {
    int nn = ty + r * 8;
    out[z + (long)(n0 + nn) * C + c0 + tx] = f2bf(tile[tx][nn]);
  }
}

__global__ __launch_bounds__(256) void cvt_bf16(
    const float* __restrict__ in, short* __restrict__ out, long n)
{
  long i = ((long)blockIdx.x * 256 + threadIdx.x) * 4;
  if (i >= n) return;
  const float* p = in + i;
  short4v s;
  s[0] = f2bf(p[0]); s[1] = f2bf(p[1]); s[2] = f2bf(p[2]); s[3] = f2bf(p[3]);
  *(short4v*)(out + i) = s;
}

__global__ void bn_prep(const float* g1, const float* b1, const float* m1, const float* v1,
                        const float* g2, const float* b2, const float* m2, const float* v2,
                        float* s1, float* t1, float* s2, float* t2)
{
  int i = threadIdx.x;
  if (i < 256) { float s = g1[i] * rsqrtf(v1[i] + 1e-5f); s1[i] = s; t1[i] = b1[i] - m1[i] * s; }
  if (i < 64)  { float s = g2[i] * rsqrtf(v2[i] + 1e-5f); s2[i] = s; t2[i] = b2[i] - m2[i] * s; }
}

// in-place row softmax over 4096 bf16 cols
__global__ __launch_bounds__(256) void softmax_row(short* __restrict__ a)
{
  __shared__ float rm[4], rs[4];
  long row = blockIdx.x;
  short* p = a + row * 4096;
  int tid = threadIdx.x;
  short8 v0 = *(short8*)(p + tid * 16);
  short8 v1 = *(short8*)(p + tid * 16 + 8);
  float f[16];
#pragma unroll
  for (int j = 0; j < 8; ++j) { f[j] = bf2f(v0[j]); f[8 + j] = bf2f(v1[j]); }
  float m = f[0];
#pragma unroll
  for (int j = 1; j < 16; ++j) m = fmaxf(m, f[j]);
  for (int o = 32; o > 0; o >>= 1) m = fmaxf(m, __shfl_xor(m, o));
  if ((tid & 63) == 0) rm[tid >> 6] = m;
  __syncthreads();
  m = fmaxf(fmaxf(rm[0], rm[1]), fmaxf(rm[2], rm[3]));
  float s = 0.f;
#pragma unroll
  for (int j = 0; j < 16; ++j) { f[j] = __expf(f[j] - m); s += f[j]; }
  for (int o = 32; o > 0; o >>= 1) s += __shfl_xor(s, o);
  if ((tid & 63) == 0) rs[tid >> 6] = s;
  __syncthreads();
  s = rs[0] + rs[1] + rs[2] + rs[3];
  float inv = 1.f / s;
#pragma unroll
  for (int j = 0; j < 8; ++j) { v0[j] = f2bf(f[j] * inv); v1[j] = f2bf(f[8 + j] * inv); }
  *(short8*)(p + tid * 16) = v0;
  *(short8*)(p + tid * 16 + 8) = v1;
}

// out[i] = sigmoid(LOG20 * (dot(y2t[i,:64], w) + bias))
__global__ __launch_bounds__(256) void c3_out(
    const short* __restrict__ y2, const float* __restrict__ w,
    const float* __restrict__ bias, float* __restrict__ o, int total)
{
  int i = blockIdx.x * 256 + threadIdx.x;
  if (i >= total) return;
  const short8* r = (const short8*)(y2 + (long)i * 64);
  float acc = 0.f;
#pragma unroll
  for (int j0 = 0; j0 < 8; ++j0) {
    short8 v = r[j0];
#pragma unroll
    for (int j = 0; j < 8; ++j) acc += bf2f(v[j]) * w[j0 * 8 + j];
  }
  acc += bias[0];
  float x = acc * LOG20F;
  o[i] = 1.f / (1.f + __expf(-x));
}

// ---------------------------------------------------------------------------
extern "C" void kernel_launch(void* const* d_in, const int* in_sizes, int n_in,
                              void* d_out, int out_size, void* d_ws, size_t ws_size,
                              hipStream_t stream) {
  const float* pcd  = (const float*)d_in[0];
  const float* img  = (const float*)d_in[1];
  const float* qw   = (const float*)d_in[2];
  const float* kw   = (const float*)d_in[3];
  const float* vw   = (const float*)d_in[4];
  const float* skw  = (const float*)d_in[5];
  const float* c1w  = (const float*)d_in[6];
  const float* bn1g = (const float*)d_in[7];
  const float* bn1b = (const float*)d_in[8];
  const float* bn1m = (const float*)d_in[9];
  const float* bn1v = (const float*)d_in[10];
  const float* c2w  = (const float*)d_in[11];
  const float* bn2g = (const float*)d_in[12];
  const float* bn2b = (const float*)d_in[13];
  const float* bn2m = (const float*)d_in[14];
  const float* bn2v = (const float*)d_in[15];
  const float* c3w  = (const float*)d_in[16];
  const float* c3b  = (const float*)d_in[17];
  float* out = (float*)d_out;

  char* ws = (char*)d_ws;
  size_t off = 0;
  auto alloc = [&](size_t bytes) {
    void* p = ws + off;
    off += (bytes + 255) & ~(size_t)255;
    return p;
  };
  const long QS = 4096L * 1024;   // per-batch elems of (4096,1024)
  short* pcdT  = (short*)alloc(8L * 4096 * 1152 * 2);   // also reused for xt
  short* imgT  = (short*)alloc(8L * 4096 * 1024 * 2);   // also reused for attn
  short* wqb   = (short*)alloc(1024L * 1152 * 2);
  short* wkb   = (short*)alloc(1024L * 1024 * 2);
  short* wvb   = (short*)alloc(1024L * 1024 * 2);
  short* wskb  = (short*)alloc(1024L * 1152 * 2);
  short* c1b   = (short*)alloc(256L * 1024 * 2);
  short* c2b   = (short*)alloc(64L * 256 * 2);
  float* s1 = (float*)alloc(256 * 4); float* t1 = (float*)alloc(256 * 4);
  float* s2 = (float*)alloc(64 * 4);  float* t2 = (float*)alloc(64 * 4);
  short* qt    = (short*)alloc(8L * QS * 2);            // reused for y1t
  short* kt    = (short*)alloc(8L * QS * 2);            // reused for y2t
  short* vbuf  = (short*)alloc(8L * QS * 2);
  short* skipT = (short*)alloc(8L * QS * 2);
  // lifetime aliases (all safely ordered on the stream):
  short* attn = imgT;    // imgT dead after kt & v GEMMs
  short* xt   = pcdT;    // pcdT dead after qt & skipT GEMMs
  short* y1t  = qt;      // qt dead after last energy GEMM
  short* y2t  = kt;      // kt dead after last energy GEMM

  // weight converts + bn prep
  cvt_bf16<<<dim3(1152), 256, 0, stream>>>(qw,  wqb,  1024L * 1152);
  cvt_bf16<<<dim3(1024), 256, 0, stream>>>(kw,  wkb,  1024L * 1024);
  cvt_bf16<<<dim3(1024), 256, 0, stream>>>(vw,  wvb,  1024L * 1024);
  cvt_bf16<<<dim3(1152), 256, 0, stream>>>(skw, wskb, 1024L * 1152);
  cvt_bf16<<<dim3(256),  256, 0, stream>>>(c1w, c1b,  256L * 1024);
  cvt_bf16<<<dim3(16),   256, 0, stream>>>(c2w, c2b,  64L * 256);
  bn_prep<<<1, 256, 0, stream>>>(bn1g, bn1b, bn1m, bn1v, bn2g, bn2b, bn2m, bn2v,
                                 s1, t1, s2, t2);
  // input transpose-converts: (8,C,4096) f32 -> (8,4096,C) bf16
  transpose_cvt<<<dim3(128, 36, 8), 256, 0, stream>>>(pcd, pcdT, 1152, 4096);
  transpose_cvt<<<dim3(128, 32, 8), 256, 0, stream>>>(img, imgT, 1024, 4096);

  // projections (all BT layout)
  // qt[n,o] = sum_c pcdT[n,c]*Wq[o,c]
  gemm_bt<128, 128, 2, 2, 0><<<dim3(32, 8, 8), 256, 0, stream>>>(
      pcdT, wqb, qt, nullptr, nullptr, nullptr,
      1152, 1152, 1152, 1024, 4096L * 1152, 0, QS, 1.f);
  // kt[m,o]
  gemm_bt<128, 128, 2, 2, 0><<<dim3(32, 8, 8), 256, 0, stream>>>(
      imgT, wkb, kt, nullptr, nullptr, nullptr,
      1024, 1024, 1024, 1024, QS, 0, QS, 1.f);
  // v[o,m] = sum_c Wv[o,c]*imgT[m,c]
  gemm_bt<128, 128, 2, 2, 0><<<dim3(8, 32, 8), 256, 0, stream>>>(
      wvb, imgT, vbuf, nullptr, nullptr, nullptr,
      1024, 1024, 1024, 4096, 0, QS, QS, 1.f);
  // skipT[n,o]
  gemm_bt<128, 128, 2, 2, 0><<<dim3(32, 8, 8), 256, 0, stream>>>(
      pcdT, wskb, skipT, nullptr, nullptr, nullptr,
      1152, 1152, 1152, 1024, 4096L * 1152, 0, QS, 1.f);

  // attention, batch at a time (attn buffer reused)
  for (int b = 0; b < 8; ++b) {
    // E[n,m] = (1/32) sum_o qt[n,o]*kt[m,o]  -> bf16, in attn buffer
    gemm_bt<128, 128, 2, 2, 0><<<dim3(32, 32, 1), 256, 0, stream>>>(
        qt + (long)b * QS, kt + (long)b * QS, attn, nullptr, nullptr, nullptr,
        1024, 1024, 1024, 4096, 0, 0, 0, 0.03125f);
    softmax_row<<<dim3(4096), 256, 0, stream>>>(attn);
    // xt[n,c] = sum_m attn[n,m]*v[c,m] + skipT[n,c]
    gemm_bt<128, 128, 2, 2, 1><<<dim3(32, 8, 1), 256, 0, stream>>>(
        attn, vbuf + (long)b * QS, xt + (long)b * QS, skipT + (long)b * QS,
        nullptr, nullptr, 4096, 4096, 4096, 1024, 0, 0, 0, 1.f);
  }

  // c1: y1t[n,o] = bnsilu(sum_c xt[n,c]*C1[o,c])
  gemm_bt<128, 128, 2, 2, 2><<<dim3(32, 2, 8), 256, 0, stream>>>(
      xt, c1b, y1t, nullptr, s1, t1,
      1024, 1024, 1024, 256, QS, 0, 4096L * 256, 1.f);
  // c2: y2t[n,p] = bnsilu(sum_o y1t[n,o]*C2[p,o])
  gemm_bt<128, 64, 4, 1, 2><<<dim3(32, 1, 8), 256, 0, stream>>>(
      y1t, c2b, y2t, nullptr, s2, t2,
      256, 256, 256, 64, 4096L * 256, 0, 4096L * 64, 1.f);
  // c3 + sigmoid
  c3_out<<<dim3(128), 256, 0, stream>>>(y2t, c3w, c3b, out, 32768);

  (void)in_sizes; (void)n_in; (void)out_size; (void)ws_size;
}

// Round 4
// 1308.469 us; speedup vs baseline: 1.2107x; 1.2107x over previous
//
#include <hip/hip_runtime.h>

#define LOG20F 2.9957322735539909f

typedef __attribute__((ext_vector_type(4))) short short4v;
typedef __attribute__((ext_vector_type(8))) short short8;
typedef __attribute__((ext_vector_type(8))) __bf16 bf16x8;
typedef __attribute__((ext_vector_type(4))) float f32x4;

__device__ __forceinline__ short f2bf(float f) {
  unsigned u = __float_as_uint(f);
  u = u + 0x7fffu + ((u >> 16) & 1u);   // RNE
  return (short)(u >> 16);
}
__device__ __forceinline__ float bf2f(short s) {
  return __uint_as_float(((unsigned)(unsigned short)s) << 16);
}

// LDS tile: [row][32 bf16], 16B chunk index XOR-swizzled: ch ^= (row>>1)&3.
// Read pattern identical to round-2 kernel (measured 0 bank conflicts).
// With global_load_lds the LDS dest must be linear (wave-uniform base +
// lane*16), so the swizzle is applied on the GLOBAL SOURCE address instead
// (rule #21: linear dest + inverse-swz source + swz on read; XOR involution).
__device__ __forceinline__ int swz(int row, int ch) {
  return row * 32 + ((ch ^ ((row >> 1) & 3)) << 3);   // offset in shorts
}

// ---------------------------------------------------------------------------
// BT GEMM: C[i,j] = sum_k A[i,k]*B[j,k], A:(M,K) ld=lda, B:(N,K) ld=ldb, both
// bf16 row-major along K. C bf16 (M,N) ld=ldc. EPI: 0=scale, 1=+add(bf16),
// 2=bn+silu (per-col scale/shift).
// ---------------------------------------------------------------------------
template <int BM, int BN, int WR, int WC, int EPI>
__global__ __launch_bounds__(256, 4) void gemm_bt(
    const short* __restrict__ A, const short* __restrict__ B,
    short* __restrict__ C, const short* __restrict__ addp,
    const float* __restrict__ sc, const float* __restrict__ sh,
    int K, int lda, int ldb, int ldc,
    long abatch, long bbatch, long cbatch, float scale)
{
  constexpr int WM = BM / WR, WN = BN / WC;
  constexpr int MR = WM / 16, NR = WN / 16;
  constexpr int CA = BM / 64, CB = BN / 64;   // 16B-chunk load rounds

  __shared__ __align__(16) short lA[2][BM * 32];
  __shared__ __align__(16) short lB[2][BN * 32];

  const int tid = threadIdx.x;
  const int lane = tid & 63;
  const int wid = tid >> 6;
  const int wr = wid / WC, wc = wid % WC;

  const long bm = (long)blockIdx.x * BM, bn = (long)blockIdx.y * BN;
  const short* Ab = A + (long)blockIdx.z * abatch + bm * lda;
  const short* Bb = B + (long)blockIdx.z * bbatch + bn * ldb;

  f32x4 acc[MR][NR] = {};

  // async global -> LDS staging; dest linear, source chunk pre-swizzled
  auto stage = [&](int buf, int k0) {
#pragma unroll
    for (int i = 0; i < CA; ++i) {
      int idx = i * 256 + tid, row = idx >> 2, ch = idx & 3;
      int chs = ch ^ ((row >> 1) & 3);
      __builtin_amdgcn_global_load_lds(
          (const __attribute__((address_space(1))) void*)(Ab + (long)row * lda + k0 + chs * 8),
          (__attribute__((address_space(3))) void*)(&lA[buf][idx * 8]),
          16, 0, 0);
    }
#pragma unroll
    for (int i = 0; i < CB; ++i) {
      int idx = i * 256 + tid, row = idx >> 2, ch = idx & 3;
      int chs = ch ^ ((row >> 1) & 3);
      __builtin_amdgcn_global_load_lds(
          (const __attribute__((address_space(1))) void*)(Bb + (long)row * ldb + k0 + chs * 8),
          (__attribute__((address_space(3))) void*)(&lB[buf][idx * 8]),
          16, 0, 0);
    }
  };

  const int NT = K >> 5;   // BK=32
  stage(0, 0);
  __syncthreads();         // implicit vmcnt(0) drain -> buf0 ready
  int cur = 0;
  for (int t = 0; t < NT; ++t) {
    if (t + 1 < NT) stage(cur ^ 1, (t + 1) << 5);   // async prefetch, other buf
    const int ch = lane >> 4, rrow = lane & 15;
    bf16x8 af[MR], bfr[NR];
#pragma unroll
    for (int mi = 0; mi < MR; ++mi) {
      int row = wr * WM + mi * 16 + rrow;
      af[mi] = *(const bf16x8*)&lA[cur][swz(row, ch)];
    }
#pragma unroll
    for (int ni = 0; ni < NR; ++ni) {
      int row = wc * WN + ni * 16 + rrow;
      bfr[ni] = *(const bf16x8*)&lB[cur][swz(row, ch)];
    }
    __builtin_amdgcn_s_setprio(1);
#pragma unroll
    for (int mi = 0; mi < MR; ++mi)
#pragma unroll
      for (int ni = 0; ni < NR; ++ni)
        acc[mi][ni] = __builtin_amdgcn_mfma_f32_16x16x32_bf16(
            af[mi], bfr[ni], acc[mi][ni], 0, 0, 0);
    __builtin_amdgcn_s_setprio(0);
    __syncthreads();       // drains vmcnt (prefetch landed) + lgkm; both bufs settled
    cur ^= 1;
  }

  // epilogue: D lane map col=lane&15, row=(lane>>4)*4+r (m89/m91)
#pragma unroll
  for (int mi = 0; mi < MR; ++mi) {
    long row0 = bm + wr * WM + mi * 16 + ((lane >> 4) << 2);
#pragma unroll
    for (int ni = 0; ni < NR; ++ni) {
      long col = bn + wc * WN + ni * 16 + (lane & 15);
#pragma unroll
      for (int r = 0; r < 4; ++r) {
        long off = (long)blockIdx.z * cbatch + (row0 + r) * ldc + col;
        float v = acc[mi][ni][r] * scale;
        if constexpr (EPI == 1) v += bf2f(addp[off]);
        if constexpr (EPI == 2) {
          float y = v * sc[col] + sh[col];
          v = y / (1.f + __expf(-y));
        }
        C[off] = f2bf(v);
      }
    }
  }
}

// ---------------------------------------------------------------------------
// (z,C,N) f32 -> (z,N,C) bf16 tiled transpose-convert
// ---------------------------------------------------------------------------
__global__ __launch_bounds__(256) void transpose_cvt(
    const float* __restrict__ in, short* __restrict__ out, int C, int N)
{
  __shared__ float tile[32][33];
  int n0 = blockIdx.x * 32, c0 = blockIdx.y * 32;
  long z = (long)blockIdx.z * C * N;
  int tx = threadIdx.x & 31, ty = threadIdx.x >> 5;   // ty 0..7
#pragma unroll
  for (int r = 0; r < 4; ++r) {
    int cc = ty + r * 8;
    tile[cc][tx] = in[z + (long)(c0 + cc) * N + n0 + tx];
  }
  __syncthreads();
#pragma unroll
  for (int r = 0; r < 4; ++r) {
    int nn = ty + r * 8;
    out[z + (long)(n0 + nn) * C + c0 + tx] = f2bf(tile[tx][nn]);
  }
}

__global__ __launch_bounds__(256) void cvt_bf16(
    const float* __restrict__ in, short* __restrict__ out, long n)
{
  long i = ((long)blockIdx.x * 256 + threadIdx.x) * 4;
  if (i >= n) return;
  const float* p = in + i;
  short4v s;
  s[0] = f2bf(p[0]); s[1] = f2bf(p[1]); s[2] = f2bf(p[2]); s[3] = f2bf(p[3]);
  *(short4v*)(out + i) = s;
}

__global__ void bn_prep(const float* g1, const float* b1, const float* m1, const float* v1,
                        const float* g2, const float* b2, const float* m2, const float* v2,
                        float* s1, float* t1, float* s2, float* t2)
{
  int i = threadIdx.x;
  if (i < 256) { float s = g1[i] * rsqrtf(v1[i] + 1e-5f); s1[i] = s; t1[i] = b1[i] - m1[i] * s; }
  if (i < 64)  { float s = g2[i] * rsqrtf(v2[i] + 1e-5f); s2[i] = s; t2[i] = b2[i] - m2[i] * s; }
}

// in-place row softmax over 4096 bf16 cols
__global__ __launch_bounds__(256) void softmax_row(short* __restrict__ a)
{
  __shared__ float rm[4], rs[4];
  long row = blockIdx.x;
  short* p = a + row * 4096;
  int tid = threadIdx.x;
  short8 v0 = *(short8*)(p + tid * 16);
  short8 v1 = *(short8*)(p + tid * 16 + 8);
  float f[16];
#pragma unroll
  for (int j = 0; j < 8; ++j) { f[j] = bf2f(v0[j]); f[8 + j] = bf2f(v1[j]); }
  float m = f[0];
#pragma unroll
  for (int j = 1; j < 16; ++j) m = fmaxf(m, f[j]);
  for (int o = 32; o > 0; o >>= 1) m = fmaxf(m, __shfl_xor(m, o));
  if ((tid & 63) == 0) rm[tid >> 6] = m;
  __syncthreads();
  m = fmaxf(fmaxf(rm[0], rm[1]), fmaxf(rm[2], rm[3]));
  float s = 0.f;
#pragma unroll
  for (int j = 0; j < 16; ++j) { f[j] = __expf(f[j] - m); s += f[j]; }
  for (int o = 32; o > 0; o >>= 1) s += __shfl_xor(s, o);
  if ((tid & 63) == 0) rs[tid >> 6] = s;
  __syncthreads();
  s = rs[0] + rs[1] + rs[2] + rs[3];
  float inv = 1.f / s;
#pragma unroll
  for (int j = 0; j < 8; ++j) { v0[j] = f2bf(f[j] * inv); v1[j] = f2bf(f[8 + j] * inv); }
  *(short8*)(p + tid * 16) = v0;
  *(short8*)(p + tid * 16 + 8) = v1;
}

// out[i] = sigmoid(LOG20 * (dot(y2t[i,:64], w) + bias))
__global__ __launch_bounds__(256) void c3_out(
    const short* __restrict__ y2, const float* __restrict__ w,
    const float* __restrict__ bias, float* __restrict__ o, int total)
{
  int i = blockIdx.x * 256 + threadIdx.x;
  if (i >= total) return;
  const short8* r = (const short8*)(y2 + (long)i * 64);
  float acc = 0.f;
#pragma unroll
  for (int j0 = 0; j0 < 8; ++j0) {
    short8 v = r[j0];
#pragma unroll
    for (int j = 0; j < 8; ++j) acc += bf2f(v[j]) * w[j0 * 8 + j];
  }
  acc += bias[0];
  float x = acc * LOG20F;
  o[i] = 1.f / (1.f + __expf(-x));
}

// ---------------------------------------------------------------------------
extern "C" void kernel_launch(void* const* d_in, const int* in_sizes, int n_in,
                              void* d_out, int out_size, void* d_ws, size_t ws_size,
                              hipStream_t stream) {
  const float* pcd  = (const float*)d_in[0];
  const float* img  = (const float*)d_in[1];
  const float* qw   = (const float*)d_in[2];
  const float* kw   = (const float*)d_in[3];
  const float* vw   = (const float*)d_in[4];
  const float* skw  = (const float*)d_in[5];
  const float* c1w  = (const float*)d_in[6];
  const float* bn1g = (const float*)d_in[7];
  const float* bn1b = (const float*)d_in[8];
  const float* bn1m = (const float*)d_in[9];
  const float* bn1v = (const float*)d_in[10];
  const float* c2w  = (const float*)d_in[11];
  const float* bn2g = (const float*)d_in[12];
  const float* bn2b = (const float*)d_in[13];
  const float* bn2m = (const float*)d_in[14];
  const float* bn2v = (const float*)d_in[15];
  const float* c3w  = (const float*)d_in[16];
  const float* c3b  = (const float*)d_in[17];
  float* out = (float*)d_out;

  char* ws = (char*)d_ws;
  size_t off = 0;
  auto alloc = [&](size_t bytes) {
    void* p = ws + off;
    off += (bytes + 255) & ~(size_t)255;
    return p;
  };
  const long QS = 4096L * 1024;   // per-batch elems of (4096,1024)
  const long ES = 4096L * 4096;   // per-batch elems of (4096,4096)
  short* pcdT  = (short*)alloc(8L * 4096 * 1152 * 2);   // also reused for xt
  short* imgT  = (short*)alloc(8L * 4096 * 1024 * 2);   // dead after kt & v
  short* wqb   = (short*)alloc(1024L * 1152 * 2);
  short* wkb   = (short*)alloc(1024L * 1024 * 2);
  short* wvb   = (short*)alloc(1024L * 1024 * 2);
  short* wskb  = (short*)alloc(1024L * 1152 * 2);
  short* c1b   = (short*)alloc(256L * 1024 * 2);
  short* c2b   = (short*)alloc(64L * 256 * 2);
  float* s1 = (float*)alloc(256 * 4); float* t1 = (float*)alloc(256 * 4);
  float* s2 = (float*)alloc(64 * 4);  float* t2 = (float*)alloc(64 * 4);
  short* qt    = (short*)alloc(8L * QS * 2);            // reused for y1t
  short* kt    = (short*)alloc(8L * QS * 2);            // reused for y2t
  short* vbuf  = (short*)alloc(8L * QS * 2);
  short* skipT = (short*)alloc(8L * QS * 2);
  // attention chunking: NB batches of energy live at once. Prefer a dedicated
  // buffer (full z-batching -> big grids); fall back to aliasing imgT
  // (exactly 2 batches: 2*ES*2B == 8*4096*1024*2B) if ws is small.
  int NB;
  short* attn;
  if (ws_size >= off + (size_t)(8L * ES * 2)) {
    NB = 8; attn = (short*)alloc(8L * ES * 2);
  } else if (ws_size >= off + (size_t)(4L * ES * 2)) {
    NB = 4; attn = (short*)alloc(4L * ES * 2);
  } else {
    NB = 2; attn = imgT;   // imgT dead by then; 64 MiB == 2 energy batches
  }
  short* xt   = pcdT;    // pcdT dead after qt & skipT GEMMs
  short* y1t  = qt;      // qt dead after last energy GEMM
  short* y2t  = kt;      // kt dead after last energy GEMM

  // weight converts + bn prep
  cvt_bf16<<<dim3(1152), 256, 0, stream>>>(qw,  wqb,  1024L * 1152);
  cvt_bf16<<<dim3(1024), 256, 0, stream>>>(kw,  wkb,  1024L * 1024);
  cvt_bf16<<<dim3(1024), 256, 0, stream>>>(vw,  wvb,  1024L * 1024);
  cvt_bf16<<<dim3(1152), 256, 0, stream>>>(skw, wskb, 1024L * 1152);
  cvt_bf16<<<dim3(256),  256, 0, stream>>>(c1w, c1b,  256L * 1024);
  cvt_bf16<<<dim3(16),   256, 0, stream>>>(c2w, c2b,  64L * 256);
  bn_prep<<<1, 256, 0, stream>>>(bn1g, bn1b, bn1m, bn1v, bn2g, bn2b, bn2m, bn2v,
                                 s1, t1, s2, t2);
  // input transpose-converts: (8,C,4096) f32 -> (8,4096,C) bf16
  transpose_cvt<<<dim3(128, 36, 8), 256, 0, stream>>>(pcd, pcdT, 1152, 4096);
  transpose_cvt<<<dim3(128, 32, 8), 256, 0, stream>>>(img, imgT, 1024, 4096);

  // projections (all BT layout)
  gemm_bt<128, 128, 2, 2, 0><<<dim3(32, 8, 8), 256, 0, stream>>>(
      pcdT, wqb, qt, nullptr, nullptr, nullptr,
      1152, 1152, 1152, 1024, 4096L * 1152, 0, QS, 1.f);
  gemm_bt<128, 128, 2, 2, 0><<<dim3(32, 8, 8), 256, 0, stream>>>(
      imgT, wkb, kt, nullptr, nullptr, nullptr,
      1024, 1024, 1024, 1024, QS, 0, QS, 1.f);
  gemm_bt<128, 128, 2, 2, 0><<<dim3(8, 32, 8), 256, 0, stream>>>(
      wvb, imgT, vbuf, nullptr, nullptr, nullptr,
      1024, 1024, 1024, 4096, 0, QS, QS, 1.f);
  gemm_bt<128, 128, 2, 2, 0><<<dim3(32, 8, 8), 256, 0, stream>>>(
      pcdT, wskb, skipT, nullptr, nullptr, nullptr,
      1152, 1152, 1152, 1024, 4096L * 1152, 0, QS, 1.f);

  // attention, NB batches per dispatch (z-batched for grid occupancy)
  for (int b0 = 0; b0 < 8; b0 += NB) {
    // E[n,m] = (1/32) sum_o qt[n,o]*kt[m,o]  -> bf16
    gemm_bt<128, 128, 2, 2, 0><<<dim3(32, 32, NB), 256, 0, stream>>>(
        qt + (long)b0 * QS, kt + (long)b0 * QS, attn, nullptr, nullptr, nullptr,
        1024, 1024, 1024, 4096, QS, QS, ES, 0.03125f);
    softmax_row<<<dim3(4096 * NB), 256, 0, stream>>>(attn);
    // xt[n,c] = sum_m attn[n,m]*v[c,m] + skipT[n,c]
    gemm_bt<128, 128, 2, 2, 1><<<dim3(32, 8, NB), 256, 0, stream>>>(
        attn, vbuf + (long)b0 * QS, xt + (long)b0 * QS, skipT + (long)b0 * QS,
        nullptr, nullptr, 4096, 4096, 4096, 1024, ES, QS, QS, 1.f);
  }

  // c1: y1t[n,o] = bnsilu(sum_c xt[n,c]*C1[o,c])
  gemm_bt<128, 128, 2, 2, 2><<<dim3(32, 2, 8), 256, 0, stream>>>(
      xt, c1b, y1t, nullptr, s1, t1,
      1024, 1024, 1024, 256, QS, 0, 4096L * 256, 1.f);
  // c2: y2t[n,p] = bnsilu(sum_o y1t[n,o]*C2[p,o])
  gemm_bt<128, 64, 4, 1, 2><<<dim3(32, 1, 8), 256, 0, stream>>>(
      y1t, c2b, y2t, nullptr, s2, t2,
      256, 256, 256, 64, 4096L * 256, 0, 4096L * 64, 1.f);
  // c3 + sigmoid
  c3_out<<<dim3(128), 256, 0, stream>>>(y2t, c3w, c3b, out, 32768);

  (void)in_sizes; (void)n_in; (void)out_size; (void)ws_size;
}